// Round 12
// baseline (224.695 us; speedup 1.0000x reference)
//
#include <hip/hip_runtime.h>

// LSTMnetwork: 3 sequential stages of h = lstm_act(inp @ Wp^T + b)
// M=8192, K=1024, packed N=3072 (f-gate dropped: i,g,o only).
// 32x32x16 MFMA variant of R11: BM=256 x BN=192, BK=32, 512 thr = 8 waves
// (4wr x 2wc, wave-tile 64x96 = 2 m-frags x {i32,g32,o32}), acc 2x3 f32x16.
// Trio-32 packing (p = hb*96 + gate*32 + hl) keeps i,g,o lane-local in the
// 32x32 C/D layout (col=lane&31, row=(reg&3)+8(reg>>2)+4(lane>>5)).
// LDS tri-buffer 84KB, 2-deep prefetch, per-wave counted WAITV, raw BAR
// (R11 skeleton verbatim). T1 XCD rect swizzle; T2 xor-swizzle (the
// (row>>1)&3 slot-xor is bank-equidistributed for 32-row frag reads).

typedef float f32x16 __attribute__((ext_vector_type(16)));
typedef short short8 __attribute__((ext_vector_type(8)));
typedef unsigned short u16;

#define NP 3072
#define MROWS 8192
#define KDIM 1024
#define BM 256
#define BN 192
#define BK 32
#define LDS_TILE 28672              // A 16KB + B 12KB per buffer; x3 = 84KB

__device__ __forceinline__ u16 f2bf(float f) {
  unsigned u = __float_as_uint(f);
  u += 0x7fffu + ((u >> 16) & 1u);   // RTNE
  return (u16)(u >> 16);
}
__device__ __forceinline__ float sigmoid_f(float x) {
  return 1.0f / (1.0f + __expf(-x));
}
__device__ __forceinline__ float tanh_f(float x) {
  float xc = fminf(fmaxf(x, -15.0f), 15.0f);
  float e = __expf(2.0f * xc);
  return (e - 1.0f) / (e + 1.0f);
}
__device__ __forceinline__ void gload_lds16(const void* g, void* l) {
  __builtin_amdgcn_global_load_lds((const __attribute__((address_space(1))) void*)g,
                                   (__attribute__((address_space(3))) void*)l,
                                   16, 0, 0);
}

// ---------------- pre-passes ----------------

__global__ __launch_bounds__(256) void k_convert_x(const float* __restrict__ x,
                                                   u16* __restrict__ out) {
  int tid = blockIdx.x * 256 + threadIdx.x;
  const float4* src = (const float4*)x + (size_t)tid * 2;
  float4 v0 = src[0], v1 = src[1];
  union { u16 u[8]; uint4 v; } r;
  r.u[0] = f2bf(v0.x); r.u[1] = f2bf(v0.y); r.u[2] = f2bf(v0.z); r.u[3] = f2bf(v0.w);
  r.u[4] = f2bf(v1.x); r.u[5] = f2bf(v1.y); r.u[6] = f2bf(v1.z); r.u[7] = f2bf(v1.w);
  ((uint4*)out)[tid] = r.v;
}

// Trio-32 packing: p = hb*96 + gs*32 + hl, hcol = hb*32 + hl = dir*512 + h.
__global__ __launch_bounds__(256) void k_pack_w(const float* __restrict__ Wih0,
                                                const float* __restrict__ Wih12,
                                                u16* __restrict__ P) {
  int tid = blockIdx.x * 256 + threadIdx.x;
  int s   = tid / (NP * 128);
  int rem = tid - s * (NP * 128);
  int p   = rem >> 7;
  int k8  = rem & 127;
  int hb = p / 96;
  int pr = p - hb * 96;
  int gs = pr >> 5;
  int hl = pr & 31;
  int hcol = hb * 32 + hl;
  int dir = hcol >> 9;
  int h   = hcol & 511;
  int og  = (gs == 0) ? 0 : (gs + 1);     // 0->i, 1->g, 2->o
  const float* src;
  if (s == 0)
    src = Wih0 + ((size_t)(dir * 2048 + og * 512 + h)) * 1024 + k8 * 8;
  else
    src = Wih12 + ((size_t)(((s - 1) * 2 + dir) * 2048 + og * 512 + h)) * 1024 + k8 * 8;
  float4 v0 = ((const float4*)src)[0];
  float4 v1 = ((const float4*)src)[1];
  union { u16 u[8]; uint4 v; } r;
  r.u[0] = f2bf(v0.x); r.u[1] = f2bf(v0.y); r.u[2] = f2bf(v0.z); r.u[3] = f2bf(v0.w);
  r.u[4] = f2bf(v1.x); r.u[5] = f2bf(v1.y); r.u[6] = f2bf(v1.z); r.u[7] = f2bf(v1.w);
  ((uint4*)P)[tid] = r.v;
}

__global__ __launch_bounds__(256) void k_pack_bias(const float* __restrict__ bih0,
                                                   const float* __restrict__ bhh0,
                                                   const float* __restrict__ bih12,
                                                   const float* __restrict__ bhh12,
                                                   float* __restrict__ pb) {
  int tid = blockIdx.x * 256 + threadIdx.x;
  if (tid >= 3 * NP) return;
  int s = tid / NP;
  int p = tid - s * NP;
  int hb = p / 96;
  int pr = p - hb * 96;
  int gs = pr >> 5;
  int hl = pr & 31;
  int hcol = hb * 32 + hl;
  int dir = hcol >> 9;
  int h   = hcol & 511;
  int og  = (gs == 0) ? 0 : (gs + 1);
  int j   = og * 512 + h;
  float v;
  if (s == 0) {
    int i = dir * 2048 + j;
    v = bih0[i] + bhh0[i];
  } else {
    int i = ((s - 1) * 2 + dir) * 2048 + j;
    v = bih12[i] + bhh12[i];
  }
  pb[tid] = v;
}

// ---------------- fused GEMM + LSTM activation ----------------

#define BAR()    __builtin_amdgcn_s_barrier()
#define SCHEDB() __builtin_amdgcn_sched_barrier(0)
#define WAITV(N) asm volatile("s_waitcnt vmcnt(" #N ")" ::: "memory")
#define MM32(Macc, Aop, Bop) Macc = __builtin_amdgcn_mfma_f32_32x32x16_bf16(Aop, Bop, Macc, 0, 0, 0)

// Stage tile KT into buffer BUF (R11 verbatim): linear LDS dest, inverse-
// swizzled source octet. Waves 0-3: 4 loads, waves 4-7: 3 (t<256 uniform).
#define STAGE(BUF, KT) \
  { char* dst = lds + (BUF) * LDS_TILE + t * 16; \
    gload_lds16(srcA + (size_t)(KT) * BK,              dst); \
    gload_lds16(srcA + 128 * KDIM + (size_t)(KT) * BK, dst + 8192); \
    gload_lds16(srcB + (size_t)(KT) * BK,              dst + 16384); \
    if (t < 256) { gload_lds16(srcB + 128 * KDIM + (size_t)(KT) * BK, dst + 24576); } }

// One K-tile (BK=32 = two K=16 steps): stage kt+2 (2-deep), read
// 4 A-frags + 6 B-frags (b128), 12 x mfma_32x32x16, counted wait, raw BAR.
#define KSTEP(RBUF, SBUF, KT, DOST, LASTT) \
  { \
    if (DOST) { STAGE(SBUF, (KT) + 2); } \
    const char* base = lds + (RBUF) * LDS_TILE; \
    short8 a00 = *(const short8*)(base + aB0 + sp0); \
    short8 a01 = *(const short8*)(base + aB0 + 2048 + sp0); \
    short8 b00 = *(const short8*)(base + bB0 + sp0); \
    short8 b01 = *(const short8*)(base + bB0 + 2048 + sp0); \
    short8 b02 = *(const short8*)(base + bB0 + 4096 + sp0); \
    short8 a10 = *(const short8*)(base + aB0 + sp1); \
    short8 a11 = *(const short8*)(base + aB0 + 2048 + sp1); \
    short8 b10 = *(const short8*)(base + bB0 + sp1); \
    short8 b11 = *(const short8*)(base + bB0 + 2048 + sp1); \
    short8 b12 = *(const short8*)(base + bB0 + 4096 + sp1); \
    __builtin_amdgcn_s_setprio(1); \
    MM32(acc00, a00, b00); MM32(acc10, a01, b00); \
    MM32(acc01, a00, b01); MM32(acc11, a01, b01); \
    MM32(acc02, a00, b02); MM32(acc12, a01, b02); \
    MM32(acc00, a10, b10); MM32(acc10, a11, b10); \
    MM32(acc01, a10, b11); MM32(acc11, a11, b11); \
    MM32(acc02, a10, b12); MM32(acc12, a11, b12); \
    __builtin_amdgcn_s_setprio(0); \
    if (DOST) { if (t < 256) { WAITV(4); } else { WAITV(3); } } \
    else if (!(LASTT)) { WAITV(0); } \
    if (!(LASTT)) { BAR(); SCHEDB(); } \
  }

template <bool F32OUT>
__global__ __launch_bounds__(512) void k_lstm_m32(const u16* __restrict__ A,
                                                  const u16* __restrict__ Bp,
                                                  const float* __restrict__ bias,
                                                  void* __restrict__ outp) {
  __shared__ __align__(16) char lds[3 * LDS_TILE];   // 84 KB
  const int t    = threadIdx.x;
  const int lane = t & 63;
  const int w    = t >> 6;          // 0..7
  const int wr   = w >> 1;          // 0..3 (M: 64-row band)
  const int wc   = w & 1;           // 0..1 (N: one 96-col macro-trio)
  const int r32  = lane & 31, sH = lane >> 5;

  // T1: bijective XCD swizzle; grid 16x32 = 512 = 8 x 64. XCD c owns an
  // 8x8 rect (8 N-cols x 8 M-bands).
  const int n_hw = blockIdx.y * gridDim.x + blockIdx.x;
  const int c    = n_hw & 7;
  const int wlc  = n_hw >> 3;          // 0..63
  const int bx   = (c & 1) * 8 + (wlc & 7);    // 0..15
  const int by   = (c >> 1) * 8 + (wlc >> 3);  // 0..31
  const int brow = by * BM;
  const int bn0  = bx * BN;

  // per-lane swizzled read bases. Logical k-octets: kstep0 -> sH, kstep1 ->
  // 2+sH; physical slot = logical ^ ((row>>1)&3); m/gs strides of 32 rows
  // leave the xor term = (r32>>1)&3 invariant.
  const int sw  = (r32 >> 1) & 3;
  const int sp0 = ((sH) ^ sw) << 4;
  const int sp1 = ((2 + sH) ^ sw) << 4;
  const int aB0 = (wr * 64 + r32) * 64;             // + mi*2048
  const int bB0 = 16384 + (wc * 96 + r32) * 64;     // + gs*2048

  // staging source (inverse-permuted octet within each 64B row; R11 verbatim)
  const int srow = t >> 2;                          // 0..127
  const int koct = ((t & 3) ^ ((t >> 3) & 3)) << 3;
  const u16* srcA = A  + (size_t)(brow + srow) * KDIM + koct;
  const u16* srcB = Bp + (size_t)(bn0  + srow) * KDIM + koct;

  f32x16 acc00, acc01, acc02, acc10, acc11, acc12;
  {
    f32x16 z;
#pragma unroll
    for (int j = 0; j < 16; ++j) z[j] = 0.f;
    acc00 = z; acc01 = z; acc02 = z; acc10 = z; acc11 = z; acc12 = z;
  }

  // prologue: stage tiles 0,1 -> bufs 0,1; drain tile0's group; barrier.
  STAGE(0, 0);
  STAGE(1, 1);
  if (t < 256) { WAITV(4); } else { WAITV(3); }
  BAR(); SCHEDB();

  // tiles 0..29 (period-3 buffers), then tail tiles 30, 31.
  for (int k3 = 0; k3 < 10; ++k3) {
    KSTEP(0, 2, k3 * 3 + 0, 1, 0);
    KSTEP(1, 0, k3 * 3 + 1, 1, 0);
    KSTEP(2, 1, k3 * 3 + 2, 1, 0);
  }
  KSTEP(0, 0, 30, 0, 0);
  KSTEP(1, 0, 31, 0, 1);

  // epilogue: wave owns one macro-trio; lane holds i,g,o for
  // hcol = (bx*2 + wc)*32 + r32; row = (j&3) + 8*(j>>2) + 4*sH (+ mi*32).
  {
    int pbase = bn0 + wc * 96;
    float biV = bias[pbase + r32];
    float bgV = bias[pbase + 32 + r32];
    float boV = bias[pbase + 64 + r32];
    int hcol = (bx * 2 + wc) * 32 + r32;
#pragma unroll
    for (int mi = 0; mi < 2; ++mi) {
      int rb = brow + wr * 64 + mi * 32 + 4 * sH;
      const f32x16& ai = mi ? acc10 : acc00;
      const f32x16& ag = mi ? acc11 : acc01;
      const f32x16& ao = mi ? acc12 : acc02;
#pragma unroll
      for (int j = 0; j < 16; ++j) {
        int grow = rb + (j & 3) + 8 * (j >> 2);
        float vi = ai[j] + biV;
        float vg = ag[j] + bgV;
        float vo = ao[j] + boV;
        float c2 = sigmoid_f(vi) * tanh_f(vg);
        float hv = sigmoid_f(vo) * tanh_f(c2);
        size_t oidx = (size_t)grow * 1024 + hcol;
        if (F32OUT) ((float*)outp)[oidx] = hv;
        else        ((u16*)outp)[oidx]   = f2bf(hv);
      }
    }
  }
}

// ---------------- launch ----------------
extern "C" void kernel_launch(void* const* d_in, const int* in_sizes, int n_in,
                              void* d_out, int out_size, void* d_ws, size_t ws_size,
                              hipStream_t stream) {
  const float* x     = (const float*)d_in[0];
  const float* Wih0  = (const float*)d_in[1];
  const float* bih0  = (const float*)d_in[3];
  const float* bhh0  = (const float*)d_in[4];
  const float* Wih12 = (const float*)d_in[5];
  const float* bih12 = (const float*)d_in[7];
  const float* bhh12 = (const float*)d_in[8];

  char* ws = (char*)d_ws;
  u16*   xbf = (u16*)ws;                       // 16,777,216 B
  u16*   h1  = (u16*)(ws + 16777216);          // 16,777,216 B
  u16*   h2  = (u16*)(ws + 33554432);          // 16,777,216 B
  u16*   P3  = (u16*)(ws + 50331648);          // 18,874,368 B
  float* pb3 = (float*)(ws + 69206016);        // 36,864 B

  k_convert_x<<<4096, 256, 0, stream>>>(x, xbf);
  k_pack_w<<<4608, 256, 0, stream>>>(Wih0, Wih12, P3);
  k_pack_bias<<<36, 256, 0, stream>>>(bih0, bhh0, bih12, bhh12, pb3);

  dim3 grid(NP / BN, MROWS / BM);   // (16, 32) = 512 blocks = 2 exact rounds
  k_lstm_m32<false><<<grid, 512, 0, stream>>>(xbf, P3, pb3, h1);
  k_lstm_m32<false><<<grid, 512, 0, stream>>>(h1, P3 + (size_t)NP * KDIM, pb3 + NP, h2);
  k_lstm_m32<true ><<<grid, 512, 0, stream>>>(h2, P3 + (size_t)2 * NP * KDIM, pb3 + 2 * NP, d_out);
}

// Round 13
// 205.422 us; speedup vs baseline: 1.0938x; 1.0938x over previous
//
#include <hip/hip_runtime.h>

// LSTMnetwork: 3 sequential stages of h = lstm_act(inp @ Wp^T + b)
// M=8192, K=1024, packed N=3072 (f-gate dropped: i,g,o only).
// R11 base (BM=256 x BN=192, BK=32, 8 waves 4wrx2wc, wave-tile 64x96,
// acc[4][6], LDS tri-buffer 84KB, 2-deep prefetch, per-wave counted WAITV,
// T1 XCD rect swizzle, T2 xor-swizzle, trio-16 packing) + THIN-PHASE
// interleave per K-tile (m201 discipline): ph0 {ds a0-3,b0-2 | stage A} BAR
// {12 MFMA n0-2} BAR; ph1 {ds b3-5 | stage B} BAR {12 MFMA n3-5} wait BAR.

typedef float f32x4 __attribute__((ext_vector_type(4)));
typedef short short8 __attribute__((ext_vector_type(8)));
typedef unsigned short u16;

#define NP 3072
#define MROWS 8192
#define KDIM 1024
#define BM 256
#define BN 192
#define BK 32
#define LDS_TILE 28672              // A 16KB + B 12KB per buffer; x3 = 84KB

__device__ __forceinline__ u16 f2bf(float f) {
  unsigned u = __float_as_uint(f);
  u += 0x7fffu + ((u >> 16) & 1u);   // RTNE
  return (u16)(u >> 16);
}
__device__ __forceinline__ float sigmoid_f(float x) {
  return 1.0f / (1.0f + __expf(-x));
}
__device__ __forceinline__ float tanh_f(float x) {
  float xc = fminf(fmaxf(x, -15.0f), 15.0f);
  float e = __expf(2.0f * xc);
  return (e - 1.0f) / (e + 1.0f);
}
__device__ __forceinline__ void gload_lds16(const void* g, void* l) {
  __builtin_amdgcn_global_load_lds((const __attribute__((address_space(1))) void*)g,
                                   (__attribute__((address_space(3))) void*)l,
                                   16, 0, 0);
}

// ---------------- pre-passes (R11 verbatim, trio-16 packing) ----------------

__global__ __launch_bounds__(256) void k_convert_x(const float* __restrict__ x,
                                                   u16* __restrict__ out) {
  int tid = blockIdx.x * 256 + threadIdx.x;
  const float4* src = (const float4*)x + (size_t)tid * 2;
  float4 v0 = src[0], v1 = src[1];
  union { u16 u[8]; uint4 v; } r;
  r.u[0] = f2bf(v0.x); r.u[1] = f2bf(v0.y); r.u[2] = f2bf(v0.z); r.u[3] = f2bf(v0.w);
  r.u[4] = f2bf(v1.x); r.u[5] = f2bf(v1.y); r.u[6] = f2bf(v1.z); r.u[7] = f2bf(v1.w);
  ((uint4*)out)[tid] = r.v;
}

__global__ __launch_bounds__(256) void k_pack_w(const float* __restrict__ Wih0,
                                                const float* __restrict__ Wih12,
                                                u16* __restrict__ P) {
  int tid = blockIdx.x * 256 + threadIdx.x;
  int s   = tid / (NP * 128);
  int rem = tid - s * (NP * 128);
  int p   = rem >> 7;
  int k8  = rem & 127;
  int hb = p / 48;
  int pr = p - hb * 48;
  int gs = pr >> 4;
  int hl = pr & 15;
  int hcol = hb * 16 + hl;
  int dir = hcol >> 9;
  int h   = hcol & 511;
  int og  = (gs == 0) ? 0 : (gs + 1);     // 0->i, 1->g, 2->o
  const float* src;
  if (s == 0)
    src = Wih0 + ((size_t)(dir * 2048 + og * 512 + h)) * 1024 + k8 * 8;
  else
    src = Wih12 + ((size_t)(((s - 1) * 2 + dir) * 2048 + og * 512 + h)) * 1024 + k8 * 8;
  float4 v0 = ((const float4*)src)[0];
  float4 v1 = ((const float4*)src)[1];
  union { u16 u[8]; uint4 v; } r;
  r.u[0] = f2bf(v0.x); r.u[1] = f2bf(v0.y); r.u[2] = f2bf(v0.z); r.u[3] = f2bf(v0.w);
  r.u[4] = f2bf(v1.x); r.u[5] = f2bf(v1.y); r.u[6] = f2bf(v1.z); r.u[7] = f2bf(v1.w);
  ((uint4*)P)[tid] = r.v;
}

__global__ __launch_bounds__(256) void k_pack_bias(const float* __restrict__ bih0,
                                                   const float* __restrict__ bhh0,
                                                   const float* __restrict__ bih12,
                                                   const float* __restrict__ bhh12,
                                                   float* __restrict__ pb) {
  int tid = blockIdx.x * 256 + threadIdx.x;
  if (tid >= 3 * NP) return;
  int s = tid / NP;
  int p = tid - s * NP;
  int hb = p / 48;
  int pr = p - hb * 48;
  int gs = pr >> 4;
  int hl = pr & 15;
  int hcol = hb * 16 + hl;
  int dir = hcol >> 9;
  int h   = hcol & 511;
  int og  = (gs == 0) ? 0 : (gs + 1);
  int j   = og * 512 + h;
  float v;
  if (s == 0) {
    int i = dir * 2048 + j;
    v = bih0[i] + bhh0[i];
  } else {
    int i = ((s - 1) * 2 + dir) * 2048 + j;
    v = bih12[i] + bhh12[i];
  }
  pb[tid] = v;
}

// ---------------- fused GEMM + LSTM activation ----------------

#define BAR()    __builtin_amdgcn_s_barrier()
#define SCHEDB() __builtin_amdgcn_sched_barrier(0)
#define WAITV(N) asm volatile("s_waitcnt vmcnt(" #N ")" ::: "memory")
#define MM(Macc, Aop, Bop) Macc = __builtin_amdgcn_mfma_f32_16x16x32_bf16(Aop, Bop, Macc, 0, 0, 0)

// One K-tile (BK=32), TWO thin phases (n-halves). Stage issue split 2+2
// (A-loads in ph0, B-loads in ph1; waves 0-3 issue 4 total, waves 4-7: 3).
// Ledger (R11): at tile entry 1 group outstanding (kt+1); this tile adds
// kt+2's group; end-of-tile WAITV(4)/(3) drains kt+1's, leaves kt+2's.
// Tail: kt=30 WAITV(0) drains kt=31's group; kt=31 no wait/barrier.
#define KSTEP(RBUF, SBUF, KT, DOST, LASTT) \
  { \
    const char* base = lds + (RBUF) * LDS_TILE; \
    short8 a0 = *(const short8*)(base + aBase); \
    short8 a1 = *(const short8*)(base + aBase + 1024); \
    short8 a2 = *(const short8*)(base + aBase + 2048); \
    short8 a3 = *(const short8*)(base + aBase + 3072); \
    short8 b0 = *(const short8*)(base + bBase); \
    short8 b1 = *(const short8*)(base + bBase + 1024); \
    short8 b2 = *(const short8*)(base + bBase + 2048); \
    if (DOST) { char* dst = lds + (SBUF) * LDS_TILE + t * 16; \
      gload_lds16(srcA + (size_t)((KT) + 2) * BK,               dst); \
      gload_lds16(srcA + 128 * KDIM + (size_t)((KT) + 2) * BK,  dst + 8192); } \
    BAR(); \
    __builtin_amdgcn_s_setprio(1); \
    MM(acc[0][0], a0, b0); MM(acc[1][0], a1, b0); MM(acc[2][0], a2, b0); MM(acc[3][0], a3, b0); \
    MM(acc[0][1], a0, b1); MM(acc[1][1], a1, b1); MM(acc[2][1], a2, b1); MM(acc[3][1], a3, b1); \
    MM(acc[0][2], a0, b2); MM(acc[1][2], a1, b2); MM(acc[2][2], a2, b2); MM(acc[3][2], a3, b2); \
    __builtin_amdgcn_s_setprio(0); \
    BAR(); \
    short8 b3 = *(const short8*)(base + bBase + 3072); \
    short8 b4 = *(const short8*)(base + bBase + 4096); \
    short8 b5 = *(const short8*)(base + bBase + 5120); \
    if (DOST) { char* dst = lds + (SBUF) * LDS_TILE + t * 16; \
      gload_lds16(srcB + (size_t)((KT) + 2) * BK,               dst + 16384); \
      if (t < 256) { gload_lds16(srcB + 128 * KDIM + (size_t)((KT) + 2) * BK, dst + 24576); } } \
    BAR(); \
    __builtin_amdgcn_s_setprio(1); \
    MM(acc[0][3], a0, b3); MM(acc[1][3], a1, b3); MM(acc[2][3], a2, b3); MM(acc[3][3], a3, b3); \
    MM(acc[0][4], a0, b4); MM(acc[1][4], a1, b4); MM(acc[2][4], a2, b4); MM(acc[3][4], a3, b4); \
    MM(acc[0][5], a0, b5); MM(acc[1][5], a1, b5); MM(acc[2][5], a2, b5); MM(acc[3][5], a3, b5); \
    __builtin_amdgcn_s_setprio(0); \
    if (DOST) { if (t < 256) { WAITV(4); } else { WAITV(3); } } \
    else if (!(LASTT)) { WAITV(0); } \
    if (!(LASTT)) { BAR(); SCHEDB(); } \
  }

template <bool F32OUT>
__global__ __launch_bounds__(512) void k_lstm_thin(const u16* __restrict__ A,
                                                   const u16* __restrict__ Bp,
                                                   const float* __restrict__ bias,
                                                   void* __restrict__ outp) {
  __shared__ __align__(16) char lds[3 * LDS_TILE];   // 84 KB
  const int t    = threadIdx.x;
  const int lane = t & 63;
  const int w    = t >> 6;          // 0..7
  const int wr   = w >> 1;          // 0..3 (M: 64-row band)
  const int wc   = w & 1;           // 0..1 (N: 96 packed cols = 2 trios)
  const int r16  = lane & 15, kg = lane >> 4;

  // T1: bijective XCD swizzle; grid 16x32 = 512 = 8 x 64. XCD c owns an
  // 8x8 rect (8 N-cols x 8 M-bands): per-XCD A 4MB + B 3MB.
  const int n_hw = blockIdx.y * gridDim.x + blockIdx.x;
  const int c    = n_hw & 7;
  const int wlc  = n_hw >> 3;          // 0..63
  const int bx   = (c & 1) * 8 + (wlc & 7);    // 0..15
  const int by   = (c >> 1) * 8 + (wlc >> 3);  // 0..31
  const int brow = by * BM;
  const int bn0  = bx * BN;

  // per-lane swizzled read bases: slot = kg ^ ((r16>>1)&3); 64B rows.
  const int slot = (kg ^ ((r16 >> 1) & 3)) << 4;
  const int aBase = wr * 4096 + r16 * 64 + slot;            // + m*1024, m 0..3
  const int bBase = 16384 + wc * 6144 + r16 * 64 + slot;    // + n*1024, n 0..5

  // staging source (inverse-permuted octet within each 64B row)
  const int srow = t >> 2;                          // 0..127
  const int koct = ((t & 3) ^ ((t >> 3) & 3)) << 3;
  const u16* srcA = A  + (size_t)(brow + srow) * KDIM + koct;
  const u16* srcB = Bp + (size_t)(bn0  + srow) * KDIM + koct;

  f32x4 acc[4][6];
#pragma unroll
  for (int m = 0; m < 4; ++m)
#pragma unroll
    for (int n = 0; n < 6; ++n) acc[m][n] = (f32x4){0.f, 0.f, 0.f, 0.f};

  // prologue: stage tiles 0,1 -> bufs 0,1 (A then B order per tile);
  // per-wave counted drain of tile0's group; barrier.
  { char* d0 = lds + t * 16;
    gload_lds16(srcA,              d0);
    gload_lds16(srcA + 128 * KDIM, d0 + 8192);
    gload_lds16(srcB,              d0 + 16384);
    if (t < 256) { gload_lds16(srcB + 128 * KDIM, d0 + 24576); }
    char* d1 = lds + LDS_TILE + t * 16;
    gload_lds16(srcA + BK,              d1);
    gload_lds16(srcA + 128 * KDIM + BK, d1 + 8192);
    gload_lds16(srcB + BK,              d1 + 16384);
    if (t < 256) { gload_lds16(srcB + 128 * KDIM + BK, d1 + 24576); } }
  if (t < 256) { WAITV(4); } else { WAITV(3); }
  BAR(); SCHEDB();

  // tiles 0..29 (period-3 buffers), then tail tiles 30, 31.
  for (int k3 = 0; k3 < 10; ++k3) {
    KSTEP(0, 2, k3 * 3 + 0, 1, 0);
    KSTEP(1, 0, k3 * 3 + 1, 1, 0);
    KSTEP(2, 1, k3 * 3 + 2, 1, 0);
  }
  KSTEP(0, 0, 30, 0, 0);
  KSTEP(1, 0, 31, 0, 1);

  // epilogue: wave owns 2 gate-trios (n = trio*3 + {i,g,o}).
#pragma unroll
  for (int trio = 0; trio < 2; ++trio) {
    int pbase = bn0 + wc * 96 + trio * 48;
    float biV = bias[pbase + r16];
    float bgV = bias[pbase + 16 + r16];
    float boV = bias[pbase + 32 + r16];
    int hcol = (bx * 4 + wc * 2 + trio) * 16 + r16;
#pragma unroll
    for (int m = 0; m < 4; ++m) {
      int rowb = brow + wr * 64 + m * 16 + kg * 4;
#pragma unroll
      for (int r = 0; r < 4; ++r) {
        float vi = acc[m][trio * 3 + 0][r] + biV;
        float vg = acc[m][trio * 3 + 1][r] + bgV;
        float vo = acc[m][trio * 3 + 2][r] + boV;
        float c2 = sigmoid_f(vi) * tanh_f(vg);
        float hv = sigmoid_f(vo) * tanh_f(c2);
        size_t oidx = (size_t)(rowb + r) * 1024 + hcol;
        if (F32OUT) ((float*)outp)[oidx] = hv;
        else        ((u16*)outp)[oidx]   = f2bf(hv);
      }
    }
  }
}

// ---------------- launch ----------------
extern "C" void kernel_launch(void* const* d_in, const int* in_sizes, int n_in,
                              void* d_out, int out_size, void* d_ws, size_t ws_size,
                              hipStream_t stream) {
  const float* x     = (const float*)d_in[0];
  const float* Wih0  = (const float*)d_in[1];
  const float* bih0  = (const float*)d_in[3];
  const float* bhh0  = (const float*)d_in[4];
  const float* Wih12 = (const float*)d_in[5];
  const float* bih12 = (const float*)d_in[7];
  const float* bhh12 = (const float*)d_in[8];

  char* ws = (char*)d_ws;
  u16*   xbf = (u16*)ws;                       // 16,777,216 B
  u16*   h1  = (u16*)(ws + 16777216);          // 16,777,216 B
  u16*   h2  = (u16*)(ws + 33554432);          // 16,777,216 B
  u16*   P3  = (u16*)(ws + 50331648);          // 18,874,368 B
  float* pb3 = (float*)(ws + 69206016);        // 36,864 B

  k_convert_x<<<4096, 256, 0, stream>>>(x, xbf);
  k_pack_w<<<4608, 256, 0, stream>>>(Wih0, Wih12, P3);
  k_pack_bias<<<36, 256, 0, stream>>>(bih0, bhh0, bih12, bhh12, pb3);

  dim3 grid(NP / BN, MROWS / BM);   // (16, 32) = 512 blocks = 2 exact rounds
  k_lstm_thin<false><<<grid, 512, 0, stream>>>(xbf, P3, pb3, h1);
  k_lstm_thin<false><<<grid, 512, 0, stream>>>(h1, P3 + (size_t)NP * KDIM, pb3 + NP, h2);
  k_lstm_thin<true ><<<grid, 512, 0, stream>>>(h2, P3 + (size_t)2 * NP * KDIM, pb3 + 2 * NP, d_out);
}